// Round 4
// baseline (253.861 us; speedup 1.0000x reference)
//
#include <hip/hip_runtime.h>
#include <stdint.h>

#define TPB_S  512
#define EPT    8
#define EPB    (TPB_S*EPT)   // 4096 edges per scatter block
#define ABITS  10
#define APB    (1<<ABITS)    // 1024 atoms per bucket -> 4 KB LDS accumulator
#define MAXB   512           // max buckets supported by fast path
#define NSH    8             // cursor/bucket shards
#define TPB_A  1024          // accum block threads == APB (1 atom/thread flush)
#define TPB_P  512           // prep block threads
#define EDROP  1e-5f         // drop records with e < EDROP (max atom err ~7e-4)

// fast reciprocal: v_rcp_f32 + 1 Newton step (rel err ~1e-7, vs 2.4e-4 pack err)
__device__ __forceinline__ float fast_rcp(float r) {
#if defined(__has_builtin)
#if __has_builtin(__builtin_amdgcn_rcpf)
    float t = __builtin_amdgcn_rcpf(r);
    return t * fmaf(-r, t, 2.0f);
#else
    return 1.0f / r;
#endif
#else
    return 1.0f / r;
#endif
}

// edge energy with hoisted K = l0^13/24:
//   e = K * r^-12 * poly_cutoff(r), p=6, r_max=6
__device__ __forceinline__ float edge_energy_k(float r, float K) {
    float x = r * (1.0f / 6.0f);
    if (x >= 1.0f) return 0.0f;
    float x2 = x * x, x3 = x2 * x, x6 = x3 * x3;
    float cut = fmaf(x6, fmaf(x, fmaf(x, -21.0f, 48.0f), -28.0f), 1.0f);
    float t  = fast_rcp(r);
    float t2 = t * t, t4 = t2 * t2;
    float t12 = t4 * t4 * t4;
    return K * t12 * cut;
}
__device__ __forceinline__ float k_of_l0(float l0) {
    float l2 = l0 * l0, l4 = l2 * l2, l8 = l4 * l4;
    return l8 * l4 * l0 * (1.0f / 24.0f);
}

// record: [28:19] local atom idx (10b), [18:0] value = fp32 bits [30:12],
// round-to-nearest at dropped 12 bits (rel err ~2.4e-4). Requires e>=0.
__device__ __forceinline__ uint32_t pack_rec(uint32_t c, float e) {
    e = fmaxf(e, 0.0f);
    uint32_t vb  = __float_as_uint(e);
    uint32_t v19 = (vb + 0x800u) >> 12;
    if (v19 > 0x7FFFFu) v19 = 0x7FFFFu;
    return ((c & (APB - 1u)) << 19) | v19;
}
__device__ __forceinline__ float unpack_val(uint32_t rec) {
    return __uint_as_float((rec & 0x7FFFFu) << 12);
}

// ---- K0: out = pae (float4), zero cursors, uniform-scales detect + K ----
__global__ __launch_bounds__(TPB_P) void k_prep(
    const float* __restrict__ scales, int tt,
    const float* __restrict__ pae, float* __restrict__ out, int N,
    uint32_t* __restrict__ cursors, uint32_t* __restrict__ uflag)
{
    int i = blockIdx.x * TPB_P + threadIdx.x;
    int i4 = i * 4;
    if (i4 + 4 <= N) {
        *(float4*)(out + i4) = *(const float4*)(pae + i4);
    } else if (i4 < N) {
        for (int j = i4; j < N; ++j) out[j] = pae[j];
    }
    if (i < MAXB * NSH) cursors[i] = 0u;
    if (blockIdx.x == 0 && threadIdx.x == 0) {
        float v0 = scales[0];
        bool same = true;
        for (int k = 1; k < tt; ++k) same &= (__float_as_uint(scales[k]) == __float_as_uint(v0));
        uflag[0] = same ? 1u : 0u;
        uflag[1] = __float_as_uint(v0);
        uflag[2] = __float_as_uint(k_of_l0(v0));
    }
}

// ---- K1: energy + EDROP filter + block-local counting sort (merged
//   histogram/rank: one LDS atomic per KEPT record) + sharded cursor
//   reservation + coalesced bucketed write. Cursor atomic issued before the
//   cs/bs write phase, consumed after -> latency hidden. ------------------
__global__ __launch_bounds__(TPB_S) void k_scatter(
    const float* __restrict__ el, const int* __restrict__ ec,
    const int* __restrict__ en, const int* __restrict__ species,
    const float* __restrict__ scales, const uint32_t* __restrict__ uflag,
    uint32_t* __restrict__ cursors, uint32_t* __restrict__ bucketed,
    float* __restrict__ out, int E, int nb, int T, int cap)
{
    __shared__ uint32_t cs[EPB];      // packed records, sorted by bucket (16 KB)
    __shared__ uint16_t bs[EPB];      // bucket of each sorted record (8 KB)
    __shared__ uint32_t cnt[MAXB], lstart[MAXB], gbase[MAXB];  // 6 KB
    __shared__ uint32_t wsum[8];

    for (int t = threadIdx.x; t < MAXB; t += TPB_S) cnt[t] = 0u;

    const uint32_t uni = uflag[0];
    const float    uK  = __uint_as_float(uflag[2]);
    const int shard = blockIdx.x & (NSH - 1);

    const int base = blockIdx.x * EPB;
    const int i0   = base + threadIdx.x * EPT;   // 8 consecutive edges/thread

    uint32_t recs[EPT]; int bkt[EPT]; uint32_t rnk[EPT];
#pragma unroll
    for (int j = 0; j < EPT; ++j) rnk[j] = 0xFFFFFFFFu;

    __syncthreads();   // cnt zero visible

    // ---- phase 1: load edges, energies, EDROP filter, rank reservation
    if (i0 + EPT <= E) {
        float4 r0 = *(const float4*)(el + i0);
        float4 r1 = *(const float4*)(el + i0 + 4);
        int4   c0 = *(const int4*)(ec + i0);
        int4   c1 = *(const int4*)(ec + i0 + 4);
        float rr[EPT] = {r0.x,r0.y,r0.z,r0.w, r1.x,r1.y,r1.z,r1.w};
        int   cc[EPT] = {c0.x,c0.y,c0.z,c0.w, c1.x,c1.y,c1.z,c1.w};
        if (uni) {
#pragma unroll
            for (int j = 0; j < EPT; ++j) {
                float e = edge_energy_k(rr[j], uK);
                if (e >= EDROP) {
                    recs[j] = pack_rec((uint32_t)cc[j], e);
                    bkt[j]  = (int)((uint32_t)cc[j] >> ABITS);
                    rnk[j]  = atomicAdd(&cnt[bkt[j]], 1u);
                }
            }
        } else {
            int4 n0 = *(const int4*)(en + i0);
            int4 n1 = *(const int4*)(en + i0 + 4);
            int  nn[EPT] = {n0.x,n0.y,n0.z,n0.w, n1.x,n1.y,n1.z,n1.w};
#pragma unroll
            for (int j = 0; j < EPT; ++j) {
                float l0 = scales[species[cc[j]] * T + species[nn[j]]];
                float e = edge_energy_k(rr[j], k_of_l0(l0));
                if (e >= EDROP) {
                    recs[j] = pack_rec((uint32_t)cc[j], e);
                    bkt[j]  = (int)((uint32_t)cc[j] >> ABITS);
                    rnk[j]  = atomicAdd(&cnt[bkt[j]], 1u);
                }
            }
        }
    } else if (i0 < E) {
        int nval = E - i0;
#pragma unroll
        for (int j = 0; j < EPT; ++j) {
            if (j < nval) {
                int i = i0 + j;
                int c = ec[i];
                float K = uni ? uK
                              : k_of_l0(scales[species[c] * T + species[en[i]]]);
                float e = edge_energy_k(el[i], K);
                if (e >= EDROP) {
                    recs[j] = pack_rec((uint32_t)c, e);
                    bkt[j]  = (int)((uint32_t)c >> ABITS);
                    rnk[j]  = atomicAdd(&cnt[bkt[j]], 1u);
                }
            }
        }
    }
    __syncthreads();

    // ---- phase 2a: wave-parallel inclusive scan of cnt (512 threads)
    const int lane = threadIdx.x & 63;
    const int wv   = threadIdx.x >> 6;
    uint32_t v = (threadIdx.x < nb) ? cnt[threadIdx.x] : 0u;
    uint32_t incl = v;
#pragma unroll
    for (int d = 1; d < 64; d <<= 1) {
        uint32_t t = __shfl_up(incl, d);
        if (lane >= d) incl += t;
    }
    if (lane == 63) wsum[wv] = incl;
    __syncthreads();

    // ---- phase 2b: exclusive offsets + ISSUE sharded cursor atomic
    uint32_t g = 0;
    {
        uint32_t add = 0;
        for (int k = 0; k < wv; ++k) add += wsum[k];
        uint32_t excl = incl + add - v;
        if (threadIdx.x < nb) {
            lstart[threadIdx.x] = excl;
            if (v) g = atomicAdd(&cursors[shard * MAXB + threadIdx.x], v);
        }
    }
    __syncthreads();

    // ---- phase 3: scatter kept records into cs/bs (covers cursor atomic)
#pragma unroll
    for (int j = 0; j < EPT; ++j) {
        if (rnk[j] != 0xFFFFFFFFu) {
            uint32_t r = lstart[bkt[j]] + rnk[j];
            cs[r] = recs[j];
            bs[r] = (uint16_t)bkt[j];
        }
    }
    // consume the atomic result only now (vmcnt wait sinks to here)
    if (threadIdx.x < nb) gbase[threadIdx.x] = g;
    __syncthreads();

    // ---- phase 4: coalesced write of sorted records to shard regions
    uint32_t tot = wsum[0] + wsum[1] + wsum[2] + wsum[3]
                 + wsum[4] + wsum[5] + wsum[6] + wsum[7];
    for (uint32_t k = threadIdx.x; k < tot; k += TPB_S) {
        int b = bs[k];
        uint32_t rec = cs[k];
        uint32_t pib = gbase[b] + (k - lstart[b]);
        if (pib < (uint32_t)cap) {
            bucketed[((size_t)b * NSH + shard) * (size_t)cap + pib] = rec;
        } else {
            // capacity overflow safety net (expected ~0 hits)
            int atom = (b << ABITS) | (int)(rec >> 19);
            atomicAdd(&out[atom], unpack_val(rec));
        }
    }
}

// ---- K2: one block per 1024-atom bucket, all 8 shards: LDS-atomic
//   accumulate (DS pipe), then ATOMIC-FREE flush: thread t owns atom t,
//   plain out[g] += acc[t] (out = pae + rare spills; single writer;
//   stream-ordered after k_scatter). No global atomics on the hot path. ---
__global__ __launch_bounds__(TPB_A) void k_accum_out(
    const uint32_t* __restrict__ bucketed, const uint32_t* __restrict__ cursors,
    float* __restrict__ out, int N, int cap)
{
    __shared__ float acc[APB];   // 4 KB
    const int b = blockIdx.x;
    acc[threadIdx.x] = 0.0f;     // TPB_A == APB
    __syncthreads();

    for (int s = 0; s < NSH; ++s) {
        uint32_t size = cursors[s * MAXB + b];
        if (size > (uint32_t)cap) size = (uint32_t)cap;
        const uint32_t* src = bucketed + ((size_t)b * NSH + s) * (size_t)cap;
        for (uint32_t k = (uint32_t)threadIdx.x * 4u; k < size; k += TPB_A * 4u) {
            if (k + 4u <= size) {
                uint4 r4 = *(const uint4*)(src + k);
                atomicAdd(&acc[r4.x >> 19], unpack_val(r4.x));
                atomicAdd(&acc[r4.y >> 19], unpack_val(r4.y));
                atomicAdd(&acc[r4.z >> 19], unpack_val(r4.z));
                atomicAdd(&acc[r4.w >> 19], unpack_val(r4.w));
            } else {
                for (uint32_t kk = k; kk < size; ++kk) {
                    uint32_t r = src[kk];
                    atomicAdd(&acc[r >> 19], unpack_val(r));
                }
            }
        }
    }
    __syncthreads();

    int g = (b << ABITS) + threadIdx.x;
    float a = acc[threadIdx.x];
    if (g < N && a != 0.0f) out[g] += a;
}

// ---- Fallback path (ws too small / too many buckets): device atomics ----
__global__ __launch_bounds__(256) void init_out_kernel(
    const float* __restrict__ pae, float* __restrict__ out, int N)
{
    int i = blockIdx.x * 256 + threadIdx.x;
    if (i < N) out[i] = pae[i];
}

__global__ __launch_bounds__(256) void edge_kernel_dev(
    const float* __restrict__ el, const int* __restrict__ ec,
    const int* __restrict__ en, const int* __restrict__ species,
    const float* __restrict__ scales, float* __restrict__ out, int E, int T)
{
    int i = blockIdx.x * 256 + threadIdx.x;
    if (i >= E) return;
    float r = el[i];
    int c = ec[i], n = en[i];
    float l0 = scales[species[c] * T + species[n]];
    float e = edge_energy_k(r, k_of_l0(l0));
    if (e >= EDROP) atomicAdd(&out[c], e);
}

extern "C" void kernel_launch(void* const* d_in, const int* in_sizes, int n_in,
                              void* d_out, int out_size, void* d_ws, size_t ws_size,
                              hipStream_t stream) {
    const float* el      = (const float*)d_in[0];
    const int*   eidx    = (const int*)  d_in[1];   // (2,E): [0:E) center, [E:2E) neighbor
    const int*   species = (const int*)  d_in[2];
    const float* pae     = (const float*)d_in[3];
    const float* scales  = (const float*)d_in[4];
    float*       out     = (float*)d_out;

    const int E = in_sizes[0];
    const int N = in_sizes[3];
    int T = 1;
    while (T * T < in_sizes[4]) ++T;   // T = 5

    const int nb  = (N + APB - 1) / APB;           // 489 buckets
    const int nb1 = (E + EPB - 1) / EPB;           // 3907 scatter blocks
    // per-(bucket,shard) capacity: ~1.125x full-E mean (16 sigma), 1024-align
    const int mean_s = E / (nb * NSH);
    const int cap = (int)(((size_t)mean_s * 9 / 8 + 1023) & ~(size_t)1023);

    size_t off = 0;
    auto take = [&](size_t bytes) { size_t o = off; off += (bytes + 15) & ~(size_t)15; return o; };
    size_t o_bucketed = take((size_t)nb * NSH * (size_t)cap * 4);
    size_t o_cursors  = take((size_t)MAXB * NSH * 4);
    size_t o_uflag    = take(16);
    const size_t need = off;

    if (nb <= MAXB && ws_size >= need) {
        char* ws = (char*)d_ws;
        uint32_t* bucketed = (uint32_t*)(ws + o_bucketed);
        uint32_t* cursors  = (uint32_t*)(ws + o_cursors);
        uint32_t* uflag    = (uint32_t*)(ws + o_uflag);

        // grid covers max(ceil(N/4), MAXB*NSH) threads
        int nthr = (N + 3) / 4;
        if (nthr < MAXB * NSH) nthr = MAXB * NSH;
        k_prep<<<(nthr + TPB_P - 1) / TPB_P, TPB_P, 0, stream>>>(
            scales, T * T, pae, out, N, cursors, uflag);
        k_scatter<<<nb1, TPB_S, 0, stream>>>(el, eidx, eidx + E, species, scales,
                                             uflag, cursors, bucketed, out,
                                             E, nb, T, cap);
        k_accum_out<<<nb, TPB_A, 0, stream>>>(bucketed, cursors, out, N, cap);
    } else {
        init_out_kernel<<<(N + 255) / 256, 256, 0, stream>>>(pae, out, N);
        edge_kernel_dev<<<(E + 255) / 256, 256, 0, stream>>>(
            el, eidx, eidx + E, species, scales, out, E, T);
    }
}